// Round 1
// baseline (1243.278 us; speedup 1.0000x reference)
//
#include <hip/hip_runtime.h>

// GraphSAGE 2-layer, mean aggregation, D=64, fp32.
// Per layer: agg[dst] += h[src] (edge scatter, float atomics),
//            out = h @ W_self + (agg/max(deg,1)) @ W_neigh + b.

#define D 64

// One thread per edge: in-degree count.
__global__ void deg_kernel(const int* __restrict__ dst, float* __restrict__ deg, int E) {
    int e = blockIdx.x * blockDim.x + threadIdx.x;
    if (e < E) atomicAdd(&deg[dst[e]], 1.0f);
}

// One wave (64 lanes) per edge; lane = feature index. Coalesced 256B gather
// from h[src], 64 float atomics into agg[dst].
__global__ void scatter_kernel(const float* __restrict__ h,
                               const int* __restrict__ src,
                               const int* __restrict__ dst,
                               float* __restrict__ agg, int E) {
    int gid  = blockIdx.x * blockDim.x + threadIdx.x;
    int edge = gid >> 6;
    int lane = threadIdx.x & 63;
    if (edge >= E) return;
    int s = src[edge];
    int d = dst[edge];
    atomicAdd(&agg[(size_t)d * D + lane], h[(size_t)s * D + lane]);
}

// One wave per node; lane = output feature d.
// out[n][d] = b[d] + sum_k h[n][k]*Wself[k][d] + (agg[n][k]/max(deg,1))*Wneigh[k][d]
// Weights staged in LDS (2 * 16 KiB). Feature row held in registers,
// broadcast across the wave via __shfl.
__global__ void __launch_bounds__(256)
sage_combine(const float* __restrict__ h,
             const float* __restrict__ agg,
             const float* __restrict__ deg,
             const float* __restrict__ Wself,
             const float* __restrict__ Wneigh,
             const float* __restrict__ bias,
             float* __restrict__ out, int N) {
    __shared__ float sWs[D * D];
    __shared__ float sWn[D * D];
    for (int i = threadIdx.x; i < D * D; i += blockDim.x) {
        sWs[i] = Wself[i];
        sWn[i] = Wneigh[i];
    }
    __syncthreads();

    int node = blockIdx.x * (blockDim.x >> 6) + (threadIdx.x >> 6);
    int d    = threadIdx.x & 63;
    if (node >= N) return;

    float invdeg = 1.0f / fmaxf(deg[node], 1.0f);
    float h_reg  = h[(size_t)node * D + d];
    float a_reg  = agg[(size_t)node * D + d] * invdeg;

    float acc = bias[d];
    #pragma unroll
    for (int k = 0; k < D; ++k) {
        float hv = __shfl(h_reg, k, 64);
        float av = __shfl(a_reg, k, 64);
        acc = fmaf(hv, sWs[k * D + d], acc);
        acc = fmaf(av, sWn[k * D + d], acc);
    }
    out[(size_t)node * D + d] = acc;
}

extern "C" void kernel_launch(void* const* d_in, const int* in_sizes, int n_in,
                              void* d_out, int out_size, void* d_ws, size_t ws_size,
                              hipStream_t stream) {
    const float* x   = (const float*)d_in[0];
    const int*   src = (const int*)d_in[1];
    const int*   dst = (const int*)d_in[2];
    const float* Ws1 = (const float*)d_in[3];
    const float* Wn1 = (const float*)d_in[4];
    const float* b1  = (const float*)d_in[5];
    const float* Ws2 = (const float*)d_in[6];
    const float* Wn2 = (const float*)d_in[7];
    const float* b2  = (const float*)d_in[8];

    const int N = in_sizes[0] / D;   // 100000
    const int E = in_sizes[1];       // 1600000

    float* out = (float*)d_out;

    // Workspace layout: deg[N] | agg[N*D] | h1[N*D]  (~52 MB)
    float* deg = (float*)d_ws;
    float* agg = deg + N;
    float* h1  = agg + (size_t)N * D;

    const int combine_blocks = (N + 3) / 4;       // 4 nodes per 256-thread block
    const int scatter_blocks = (E + 3) / 4;       // 4 edges per 256-thread block

    // ---- degree (shared by both layers) ----
    hipMemsetAsync(deg, 0, (size_t)N * sizeof(float), stream);
    deg_kernel<<<(E + 255) / 256, 256, 0, stream>>>(dst, deg, E);

    // ---- layer 1 ----
    hipMemsetAsync(agg, 0, (size_t)N * D * sizeof(float), stream);
    scatter_kernel<<<scatter_blocks, 256, 0, stream>>>(x, src, dst, agg, E);
    sage_combine<<<combine_blocks, 256, 0, stream>>>(x, agg, deg, Ws1, Wn1, b1, h1, N);

    // ---- layer 2 ----
    hipMemsetAsync(agg, 0, (size_t)N * D * sizeof(float), stream);
    scatter_kernel<<<scatter_blocks, 256, 0, stream>>>(h1, src, dst, agg, E);
    sage_combine<<<combine_blocks, 256, 0, stream>>>(h1, agg, deg, Ws2, Wn2, b2, out, N);
}

// Round 2
// 980.991 us; speedup vs baseline: 1.2674x; 1.2674x over previous
//
#include <hip/hip_runtime.h>

// GraphSAGE 2-layer, mean agg, D=64, fp32 — CSR-gather formulation.
// Per call: build CSR by dst (count -> scan -> fill), then per layer one fused
// kernel: wave-per-node gather-sum of neighbor rows + dual GEMV (LDS weights).

#define D 64

// ---- CSR build ----------------------------------------------------------

__global__ void count_kernel(const int* __restrict__ dst, int* __restrict__ counts, int E) {
    int e = blockIdx.x * blockDim.x + threadIdx.x;
    if (e < E) atomicAdd(&counts[dst[e]], 1);
}

// Each block of 256 threads sums 256 counts -> partial[blockIdx].
__global__ void partial_kernel(const int* __restrict__ counts, int* __restrict__ partial, int N) {
    __shared__ int s[256];
    int i = blockIdx.x * 256 + threadIdx.x;
    s[threadIdx.x] = (i < N) ? counts[i] : 0;
    __syncthreads();
    for (int off = 128; off > 0; off >>= 1) {
        if (threadIdx.x < off) s[threadIdx.x] += s[threadIdx.x + off];
        __syncthreads();
    }
    if (threadIdx.x == 0) partial[blockIdx.x] = s[0];
}

// Exclusive scan of partials in one block (P <= 1024).
__global__ void scan_partial_kernel(int* __restrict__ partial, int P) {
    __shared__ int s[1024];
    for (int i = threadIdx.x; i < P; i += blockDim.x) s[i] = partial[i];
    __syncthreads();
    if (threadIdx.x == 0) {
        int run = 0;
        for (int i = 0; i < P; ++i) { int v = s[i]; s[i] = run; run += v; }
    }
    __syncthreads();
    for (int i = threadIdx.x; i < P; i += blockDim.x) partial[i] = s[i];
}

// Per-block exclusive scan of counts + block offset -> row_start, cursor.
__global__ void scan_kernel(const int* __restrict__ counts, const int* __restrict__ partial,
                            int* __restrict__ row_start, int* __restrict__ cursor, int N) {
    __shared__ int s[256];
    int i = blockIdx.x * 256 + threadIdx.x;
    int v = (i < N) ? counts[i] : 0;
    s[threadIdx.x] = v;
    __syncthreads();
    for (int off = 1; off < 256; off <<= 1) {
        int t = (threadIdx.x >= off) ? s[threadIdx.x - off] : 0;
        __syncthreads();
        s[threadIdx.x] += t;
        __syncthreads();
    }
    if (i < N) {
        int excl = s[threadIdx.x] - v + partial[blockIdx.x];
        row_start[i] = excl;
        cursor[i]    = excl;
    }
}

__global__ void fill_kernel(const int* __restrict__ src, const int* __restrict__ dst,
                            int* __restrict__ cursor, int* __restrict__ edge_src, int E) {
    int e = blockIdx.x * blockDim.x + threadIdx.x;
    if (e < E) {
        int pos = atomicAdd(&cursor[dst[e]], 1);
        edge_src[pos] = src[e];
    }
}

// ---- Fused layer: gather-mean + fc_self + fc_neigh + bias ---------------
// One wave per node, lane = feature. Edge srcs loaded coalesced (one lane per
// edge), broadcast via shfl; neighbor rows gathered as 256B coalesced reads.

__global__ void __launch_bounds__(256)
sage_layer(const float* __restrict__ h,
           const int* __restrict__ row_start,
           const int* __restrict__ counts,
           const int* __restrict__ edge_src,
           const float* __restrict__ Wself,
           const float* __restrict__ Wneigh,
           const float* __restrict__ bias,
           float* __restrict__ out, int N) {
    __shared__ float sWs[D * D];
    __shared__ float sWn[D * D];
    for (int i = threadIdx.x; i < D * D; i += blockDim.x) {
        sWs[i] = Wself[i];
        sWn[i] = Wneigh[i];
    }
    __syncthreads();

    int node = blockIdx.x * (blockDim.x >> 6) + (threadIdx.x >> 6);
    int lane = threadIdx.x & 63;
    if (node >= N) return;

    int start = row_start[node];
    int cnt   = counts[node];

    float hv  = h[(size_t)node * D + lane];
    float acc = 0.0f;

    int j = 0;
    while (j < cnt) {
        int chunk = min(cnt - j, 64);
        int sreg  = (lane < chunk) ? edge_src[start + j + lane] : 0;
        for (int t = 0; t < chunk; ++t) {
            int s = __shfl(sreg, t, 64);
            acc += h[(size_t)s * D + lane];
        }
        j += chunk;
    }

    float av = acc * (1.0f / fmaxf((float)cnt, 1.0f));

    float o = bias[lane];
    #pragma unroll
    for (int k = 0; k < D; ++k) {
        float a = __shfl(hv, k, 64);
        float b = __shfl(av, k, 64);
        o = fmaf(a, sWs[k * D + lane], o);
        o = fmaf(b, sWn[k * D + lane], o);
    }
    out[(size_t)node * D + lane] = o;
}

// -------------------------------------------------------------------------

extern "C" void kernel_launch(void* const* d_in, const int* in_sizes, int n_in,
                              void* d_out, int out_size, void* d_ws, size_t ws_size,
                              hipStream_t stream) {
    const float* x   = (const float*)d_in[0];
    const int*   src = (const int*)d_in[1];
    const int*   dst = (const int*)d_in[2];
    const float* Ws1 = (const float*)d_in[3];
    const float* Wn1 = (const float*)d_in[4];
    const float* b1  = (const float*)d_in[5];
    const float* Ws2 = (const float*)d_in[6];
    const float* Wn2 = (const float*)d_in[7];
    const float* b2  = (const float*)d_in[8];

    const int N = in_sizes[0] / D;   // 100000
    const int E = in_sizes[1];       // 1600000

    float* out = (float*)d_out;

    const int P = (N + 255) / 256;   // number of scan partials (391)

    // Workspace layout (ints then floats): counts[N] | row_start[N] | cursor[N]
    //   | partial[P(pad 1024)] | edge_src[E] | h1[N*D]   (~34 MB)
    int* counts    = (int*)d_ws;
    int* row_start = counts + N;
    int* cursor    = row_start + N;
    int* partial   = cursor + N;
    int* edge_src  = partial + 1024;
    float* h1      = (float*)(edge_src + E);

    // ---- CSR build (reused by both layers) ----
    hipMemsetAsync(counts, 0, (size_t)N * sizeof(int), stream);
    count_kernel<<<(E + 255) / 256, 256, 0, stream>>>(dst, counts, E);
    partial_kernel<<<P, 256, 0, stream>>>(counts, partial, N);
    scan_partial_kernel<<<1, 1024, 0, stream>>>(partial, P);
    scan_kernel<<<P, 256, 0, stream>>>(counts, partial, row_start, cursor, N);
    fill_kernel<<<(E + 255) / 256, 256, 0, stream>>>(src, dst, cursor, edge_src, E);

    const int layer_blocks = (N + 3) / 4;  // 4 nodes per 256-thread block

    // ---- layer 1 ----
    sage_layer<<<layer_blocks, 256, 0, stream>>>(x, row_start, counts, edge_src,
                                                 Ws1, Wn1, b1, h1, N);
    // ---- layer 2 ----
    sage_layer<<<layer_blocks, 256, 0, stream>>>(h1, row_start, counts, edge_src,
                                                 Ws2, Wn2, b2, out, N);
}

// Round 3
// 669.546 us; speedup vs baseline: 1.8569x; 1.4652x over previous
//
#include <hip/hip_runtime.h>

// GraphSAGE 2-layer, mean agg, D=64, fp32 — CSR gather + fused dual-GEMV.
// R3: float4 gather w/ 4 accumulators, v_readlane GEMV broadcast (SALU),
//     interleaved float2 weight LDS reads, grid-stride node loop.

#define D 64

// ---- CSR build ----------------------------------------------------------

__global__ void count_kernel(const int* __restrict__ dst, int* __restrict__ counts, int E) {
    int e = blockIdx.x * blockDim.x + threadIdx.x;
    if (e < E) atomicAdd(&counts[dst[e]], 1);
}

__global__ void partial_kernel(const int* __restrict__ counts, int* __restrict__ partial, int N) {
    __shared__ int s[256];
    int i = blockIdx.x * 256 + threadIdx.x;
    s[threadIdx.x] = (i < N) ? counts[i] : 0;
    __syncthreads();
    for (int off = 128; off > 0; off >>= 1) {
        if (threadIdx.x < off) s[threadIdx.x] += s[threadIdx.x + off];
        __syncthreads();
    }
    if (threadIdx.x == 0) partial[blockIdx.x] = s[0];
}

__global__ void scan_partial_kernel(int* __restrict__ partial, int P) {
    __shared__ int s[1024];
    for (int i = threadIdx.x; i < P; i += blockDim.x) s[i] = partial[i];
    __syncthreads();
    if (threadIdx.x == 0) {
        int run = 0;
        for (int i = 0; i < P; ++i) { int v = s[i]; s[i] = run; run += v; }
    }
    __syncthreads();
    for (int i = threadIdx.x; i < P; i += blockDim.x) partial[i] = s[i];
}

__global__ void scan_kernel(const int* __restrict__ counts, const int* __restrict__ partial,
                            int* __restrict__ row_start, int* __restrict__ cursor, int N) {
    __shared__ int s[256];
    int i = blockIdx.x * 256 + threadIdx.x;
    int v = (i < N) ? counts[i] : 0;
    s[threadIdx.x] = v;
    __syncthreads();
    for (int off = 1; off < 256; off <<= 1) {
        int t = (threadIdx.x >= off) ? s[threadIdx.x - off] : 0;
        __syncthreads();
        s[threadIdx.x] += t;
        __syncthreads();
    }
    if (i < N) {
        int excl = s[threadIdx.x] - v + partial[blockIdx.x];
        row_start[i] = excl;
        cursor[i]    = excl;
    }
}

__global__ void fill_kernel(const int* __restrict__ src, const int* __restrict__ dst,
                            int* __restrict__ cursor, int* __restrict__ edge_src, int E) {
    int e = blockIdx.x * blockDim.x + threadIdx.x;
    if (e < E) {
        int pos = atomicAdd(&cursor[dst[e]], 1);
        edge_src[pos] = src[e];
    }
}

// ---- Fused layer --------------------------------------------------------

__device__ __forceinline__ float rl(float v, int lane) {
    return __int_as_float(__builtin_amdgcn_readlane(__float_as_int(v), lane));
}

__global__ void __launch_bounds__(256)
sage_layer(const float* __restrict__ h,
           const int* __restrict__ row_start,
           const int* __restrict__ counts,
           const int* __restrict__ edge_src,
           const float* __restrict__ Wself,
           const float* __restrict__ Wneigh,
           const float* __restrict__ bias,
           float* __restrict__ out, int N) {
    __shared__ float2 sW[D * D];   // interleaved (Wself[k][d], Wneigh[k][d])
    for (int i = threadIdx.x; i < D * D; i += blockDim.x)
        sW[i] = make_float2(Wself[i], Wneigh[i]);
    __syncthreads();

    const int lane = threadIdx.x & 63;
    const int q    = lane & 15;    // float4 column: features 4q..4q+3
    const int g    = lane >> 4;    // edge subgroup 0..3
    const int wave_id = blockIdx.x * (blockDim.x >> 6) + (threadIdx.x >> 6);
    const int n_waves = gridDim.x * (blockDim.x >> 6);

    const float bmy = bias[lane];

    for (int node = wave_id; node < N; node += n_waves) {
        const int start = row_start[node];
        const int cnt   = counts[node];

        float4 a0 = {0,0,0,0}, a1 = {0,0,0,0}, a2 = {0,0,0,0}, a3 = {0,0,0,0};

        for (int j = 0; j < cnt; j += 64) {
            const int chunk = min(cnt - j, 64);
            const int sreg  = (lane < chunk) ? edge_src[start + j + lane] : 0;
            for (int t = 0; t < chunk; t += 16) {
                const int e0 = t + 0 + g, e1 = t + 4 + g, e2 = t + 8 + g, e3 = t + 12 + g;
                const int s0 = __shfl(sreg, e0, 64);
                const int s1 = __shfl(sreg, e1, 64);
                const int s2 = __shfl(sreg, e2, 64);
                const int s3 = __shfl(sreg, e3, 64);
                if (e0 < chunk) { float4 v = *(const float4*)&h[(size_t)s0 * D + 4 * q];
                                  a0.x += v.x; a0.y += v.y; a0.z += v.z; a0.w += v.w; }
                if (e1 < chunk) { float4 v = *(const float4*)&h[(size_t)s1 * D + 4 * q];
                                  a1.x += v.x; a1.y += v.y; a1.z += v.z; a1.w += v.w; }
                if (e2 < chunk) { float4 v = *(const float4*)&h[(size_t)s2 * D + 4 * q];
                                  a2.x += v.x; a2.y += v.y; a2.z += v.z; a2.w += v.w; }
                if (e3 < chunk) { float4 v = *(const float4*)&h[(size_t)s3 * D + 4 * q];
                                  a3.x += v.x; a3.y += v.y; a3.z += v.z; a3.w += v.w; }
            }
        }

        float4 acc;
        acc.x = (a0.x + a1.x) + (a2.x + a3.x);
        acc.y = (a0.y + a1.y) + (a2.y + a3.y);
        acc.z = (a0.z + a1.z) + (a2.z + a3.z);
        acc.w = (a0.w + a1.w) + (a2.w + a3.w);
        // reduce across the 4 subgroups (lane bits 4 and 5)
        acc.x += __shfl_xor(acc.x, 16, 64);  acc.x += __shfl_xor(acc.x, 32, 64);
        acc.y += __shfl_xor(acc.y, 16, 64);  acc.y += __shfl_xor(acc.y, 32, 64);
        acc.z += __shfl_xor(acc.z, 16, 64);  acc.z += __shfl_xor(acc.z, 32, 64);
        acc.w += __shfl_xor(acc.w, 16, 64);  acc.w += __shfl_xor(acc.w, 32, 64);

        const float inv = 1.0f / fmaxf((float)cnt, 1.0f);
        float4 av = {acc.x * inv, acc.y * inv, acc.z * inv, acc.w * inv};
        float4 hv = *(const float4*)&h[(size_t)node * D + 4 * q];

        float o = bmy;
        #pragma unroll
        for (int k = 0; k < D; ++k) {
            const float2 w = sW[k * D + lane];
            const float hc = (k & 3) == 0 ? hv.x : (k & 3) == 1 ? hv.y : (k & 3) == 2 ? hv.z : hv.w;
            const float ac = (k & 3) == 0 ? av.x : (k & 3) == 1 ? av.y : (k & 3) == 2 ? av.z : av.w;
            const float hk = rl(hc, k >> 2);   // v_readlane: SALU, constant lane
            const float ak = rl(ac, k >> 2);
            o = fmaf(hk, w.x, o);
            o = fmaf(ak, w.y, o);
        }
        out[(size_t)node * D + lane] = o;
    }
}

// -------------------------------------------------------------------------

extern "C" void kernel_launch(void* const* d_in, const int* in_sizes, int n_in,
                              void* d_out, int out_size, void* d_ws, size_t ws_size,
                              hipStream_t stream) {
    const float* x   = (const float*)d_in[0];
    const int*   src = (const int*)d_in[1];
    const int*   dst = (const int*)d_in[2];
    const float* Ws1 = (const float*)d_in[3];
    const float* Wn1 = (const float*)d_in[4];
    const float* b1  = (const float*)d_in[5];
    const float* Ws2 = (const float*)d_in[6];
    const float* Wn2 = (const float*)d_in[7];
    const float* b2  = (const float*)d_in[8];

    const int N = in_sizes[0] / D;   // 100000
    const int E = in_sizes[1];       // 1600000

    float* out = (float*)d_out;

    const int P = (N + 255) / 256;

    // Workspace: counts[N] | row_start[N] | cursor[N] | partial[1024] | edge_src[E] | h1[N*D]
    int* counts    = (int*)d_ws;
    int* row_start = counts + N;
    int* cursor    = row_start + N;
    int* partial   = cursor + N;
    int* edge_src  = partial + 1024;
    float* h1      = (float*)(edge_src + E);

    // ---- CSR build ----
    hipMemsetAsync(counts, 0, (size_t)N * sizeof(int), stream);
    count_kernel<<<(E + 255) / 256, 256, 0, stream>>>(dst, counts, E);
    partial_kernel<<<P, 256, 0, stream>>>(counts, partial, N);
    scan_partial_kernel<<<1, 1024, 0, stream>>>(partial, P);
    scan_kernel<<<P, 256, 0, stream>>>(counts, partial, row_start, cursor, N);
    fill_kernel<<<(E + 255) / 256, 256, 0, stream>>>(src, dst, cursor, edge_src, E);

    // ---- layers (grid-stride; 1280 blocks = 5 blocks/CU at 32 KB LDS) ----
    const int layer_blocks = 1280;
    sage_layer<<<layer_blocks, 256, 0, stream>>>(x, row_start, counts, edge_src,
                                                 Ws1, Wn1, b1, h1, N);
    sage_layer<<<layer_blocks, 256, 0, stream>>>(h1, row_start, counts, edge_src,
                                                 Ws2, Wn2, b2, out, N);
}